// Round 7
// baseline (179.454 us; speedup 1.0000x reference)
//
#include <hip/hip_runtime.h>

#define W      512
#define IMG    (512 * 512)
#define NB     16
#define NPIX   (NB * IMG)
#define BLOCK  256
#define NEDT   512     // 16 img x 32 row-groups (16 rows/block; 4 rows/wave)
#define NLOSS  512     // 16 img x 16 col-groups(32 cols) x 2 row-halves
#define NTOT   (NEDT + NLOSS)

struct WS {
    unsigned int done;               // memset 0 each launch (4 bytes)
    unsigned int ebmax[NEDT * 4];    // per-EDT-wave max d^2 (plain stores)
    float rows[NB * W];              // w_edt[b, h=b, :]
    float colpart[NLOSS][32];        // per-loss-block column sums of t*d^2
    float lpart[NLOSS][8];           // per-loss-block {pt, pp, st, C, A}
};

// Exactness fallback (P ~ 2^-47 per pixel) — one copy, never inlined.
__device__ __noinline__ int brute_force(const float* __restrict__ img, int h, int y) {
    int nb = 100000000;   // reference BIG when image has no zeros
    for (int gh = 0; gh < W; ++gh) {
        int dhh = gh - h, dh2 = dhh * dhh;
        if (dh2 >= nb) continue;
        const float* rp = img + (gh << 9);
        for (int yy = 0; yy < W; ++yy)
            if (rp[yy] == 0.0f) { int dx = yy - y; nb = min(nb, dh2 + dx * dx); }
    }
    return nb;
}

__global__ __launch_bounds__(BLOCK) void fused_kernel(const float* __restrict__ inp,
                                                      const float* __restrict__ tgt,
                                                      WS* __restrict__ ws,
                                                      float* __restrict__ out) {
    __shared__ float cmat[32][33];   // loss col-sum transpose (pad: conflict-free)
    __shared__ float sredf[4][8];
    __shared__ float fvmax[16], Aimg[16];
    __shared__ double shd[4][6];
    __shared__ int   slast;

    int blk = blockIdx.x, tid = threadIdx.x;
    int wv = tid >> 6, lane = tid & 63;

    if (blk < NEDT) {
        // ================= EDT role: full-row ballot pipeline =================
        int b   = blk >> 5;
        int grp = blk & 31;
        int r0  = (grp << 4) + (wv << 2);    // wave's first output row (4 rows)
        const float* img = tgt + (size_t)b * IMG;

        float buf[4][8];                     // 3-row lookahead (constant-indexed)
        unsigned int P0 = 0, P1 = 0, P2 = 0, P3 = 0, P4 = 0, P5 = 0, P6 = 0;
        unsigned int bmax = 0;

        auto loadrow = [&](int i) {
            int rr = r0 - 3 + i;
            float* d = buf[i & 3];
            if (rr >= 0 && rr < W) {         // wave-uniform
                const float* rp = img + (rr << 9);
                #pragma unroll
                for (int k = 0; k < 8; ++k) d[k] = rp[(k << 6) + lane];
            } else {
                #pragma unroll
                for (int k = 0; k < 8; ++k) d[k] = 1.0f;
            }
        };

        loadrow(0); loadrow(1); loadrow(2);
        #pragma unroll
        for (int i = 0; i < 10; ++i) {
            if (i + 3 < 10) loadrow(i + 3);
            const float* v = buf[i & 3];
            unsigned long long B[8];
            #pragma unroll
            for (int k = 0; k < 8; ++k) B[k] = __ballot(v[k] == 0.0f);
            unsigned int Dn = 0;
            #pragma unroll
            for (int k = 0; k < 8; ++k) {
                unsigned long long Bm = k ? B[k - 1] : 0ULL;
                unsigned long long Bp = (k < 7) ? B[k + 1] : 0ULL;
                unsigned long long lo = (B[k] << 4) | (Bm >> 60);
                unsigned long long hi = (B[k] >> 60) | (Bp << 4);
                unsigned int win = (unsigned int)(((lo >> lane) |
                                   ((hi << (63 - lane)) << 1)) & 0x1FFULL);
                int dr = __builtin_ctz((win >> 4) | 0x20u);      // 0..5
                unsigned int lb = win & 0xFu;                     // cols y-1..y-4
                int dl = lb ? (__builtin_clz(lb) - 27) : 5;
                Dn |= (unsigned int)min(dr, dl) << (k << 2);
            }
            P0 = P1; P1 = P2; P2 = P3; P3 = P4; P4 = P5; P5 = P6; P6 = Dn;
            if (i >= 6) {
                int er = r0 + i - 6;
                #pragma unroll
                for (int k = 0; k < 8; ++k) {
                    int sh = k << 2;
                    int d3 = (P3 >> sh) & 15;
                    int m1 = min((P2 >> sh) & 15, (P4 >> sh) & 15);
                    int m2 = min((P1 >> sh) & 15, (P5 >> sh) & 15);
                    int m3 = min((P0 >> sh) & 15, (P6 >> sh) & 15);
                    int best = min(min(d3 * d3, 1 + m1 * m1),
                                   min(4 + m2 * m2, 9 + m3 * m3));
                    if (best > 16) best = brute_force(img, er, (k << 6) + lane);
                    if (er == b) ws->rows[(b << 9) + (k << 6) + lane] = sqrtf((float)best);
                    bmax = max(bmax, (unsigned int)best);
                }
            }
        }
        #pragma unroll
        for (int o = 32; o > 0; o >>= 1)
            bmax = max(bmax, (unsigned int)__shfl_down((int)bmax, o));
        if (lane == 0) ws->ebmax[(blk << 2) + wv] = bmax;
    } else {
        // ================= loss role: float4, column-complete =================
        int lid  = blk - NEDT;           // 0..511
        int b    = lid >> 5;
        int cg   = (lid >> 1) & 15;      // 32-column group
        int half = lid & 1;
        int c4   = tid & 7;              // float4 index within group
        int r    = tid >> 3;             // 0..31
        const float4* ip = (const float4*)(inp + (size_t)b * IMG);
        const float4* tp = (const float4*)(tgt + (size_t)b * IMG);
        int colbase4 = (cg << 3) + c4;   // float4 column within row (128/row)

        float4 cs = make_float4(0.f, 0.f, 0.f, 0.f);
        float pt = 0.f, pp = 0.f, st = 0.f, Cc = 0.f, Aa = 0.f;
        #pragma unroll
        for (int k = 0; k < 8; ++k) {
            int row = (half << 8) + (r << 3) + k;
            int idx = (row << 7) + colbase4;
            float4 x = ip[idx], t = tp[idx];
            {
                float d = x.x - t.x, dd = d * d; Cc += dd;
                float td2 = t.x * dd; Aa += td2; cs.x += td2;
                float p = 1.0f / (1.0f + __expf(-x.x));
                pt += p * t.x; pp += p; st += t.x;
            }
            {
                float d = x.y - t.y, dd = d * d; Cc += dd;
                float td2 = t.y * dd; Aa += td2; cs.y += td2;
                float p = 1.0f / (1.0f + __expf(-x.y));
                pt += p * t.y; pp += p; st += t.y;
            }
            {
                float d = x.z - t.z, dd = d * d; Cc += dd;
                float td2 = t.z * dd; Aa += td2; cs.z += td2;
                float p = 1.0f / (1.0f + __expf(-x.z));
                pt += p * t.z; pp += p; st += t.z;
            }
            {
                float d = x.w - t.w, dd = d * d; Cc += dd;
                float td2 = t.w * dd; Aa += td2; cs.w += td2;
                float p = 1.0f / (1.0f + __expf(-x.w));
                pt += p * t.w; pp += p; st += t.w;
            }
        }
        cmat[r][(c4 << 2) + 0] = cs.x;
        cmat[r][(c4 << 2) + 1] = cs.y;
        cmat[r][(c4 << 2) + 2] = cs.z;
        cmat[r][(c4 << 2) + 3] = cs.w;
        #pragma unroll
        for (int o = 32; o > 0; o >>= 1) {
            pt += __shfl_down(pt, o); pp += __shfl_down(pp, o);
            st += __shfl_down(st, o); Cc += __shfl_down(Cc, o);
            Aa += __shfl_down(Aa, o);
        }
        if (lane == 0) { sredf[wv][0] = pt; sredf[wv][1] = pp; sredf[wv][2] = st;
                         sredf[wv][3] = Cc; sredf[wv][4] = Aa; }
        __syncthreads();
        if (tid < 32) {
            float s = 0.f;
            #pragma unroll
            for (int rr = 0; rr < 32; ++rr) s += cmat[rr][tid];
            ws->colpart[lid][tid] = s;
        }
        if (tid == 0) {
            float a0 = 0, a1 = 0, a2 = 0, a3 = 0, a4 = 0;
            #pragma unroll
            for (int i = 0; i < 4; ++i) {
                a0 += sredf[i][0]; a1 += sredf[i][1]; a2 += sredf[i][2];
                a3 += sredf[i][3]; a4 += sredf[i][4];
            }
            float* pr = ws->lpart[lid];
            pr[0] = a0; pr[1] = a1; pr[2] = a2; pr[3] = a3; pr[4] = a4;
        }
    }

    // ============ last-block finalize (device-scope handshake) ============
    __threadfence();
    __syncthreads();
    if (tid == 0)
        slast = (atomicAdd(&ws->done, 1u) == (unsigned int)(NTOT - 1));
    __syncthreads();
    if (!slast) return;
    __threadfence();   // acquire

    // per-image vmax (16 threads/image over 128 slots) and A_b (32 lpart rows)
    int bimg = tid >> 4, j = tid & 15;
    unsigned int mx = 0;
    #pragma unroll
    for (int k = 0; k < 8; ++k)
        mx = max(mx, ws->ebmax[(bimg << 7) + (j << 3) + k]);
    float a4 = ws->lpart[(bimg << 5) + j][4] + ws->lpart[(bimg << 5) + 16 + j][4];
    #pragma unroll
    for (int o = 8; o > 0; o >>= 1) {
        mx = max(mx, (unsigned int)__shfl_down((int)mx, o));
        a4 += __shfl_down(a4, o);
    }
    if (j == 0) { fvmax[bimg] = sqrtf((float)mx); Aimg[bimg] = a4; }

    double pt = 0, pp = 0, st = 0, C = 0;
    {
        const float* p0 = ws->lpart[tid];
        const float* p1 = ws->lpart[tid + 256];
        pt = (double)p0[0] + p1[0]; pp = (double)p0[1] + p1[1];
        st = (double)p0[2] + p1[2]; C  = (double)p0[3] + p1[3];
    }
    __syncthreads();

    double dot = 0.0;
    for (int i = tid; i < NB * W; i += BLOCK) {
        int bb = i >> 9, y = i & 511;
        int lidb = (bb << 5) + ((y >> 5) << 1);
        float scol = ws->colpart[lidb][y & 31] + ws->colpart[lidb + 1][y & 31];
        dot += (double)ws->rows[i] * (double)scol;
    }
    double vA = (tid < 16) ? (double)fvmax[tid] * (double)Aimg[tid] : 0.0;

    #pragma unroll
    for (int o = 32; o > 0; o >>= 1) {
        pt += __shfl_down(pt, o); pp += __shfl_down(pp, o);
        st += __shfl_down(st, o); C  += __shfl_down(C, o);
        dot += __shfl_down(dot, o); vA += __shfl_down(vA, o);
    }
    if (lane == 0) { shd[wv][0] = pt; shd[wv][1] = pp; shd[wv][2] = st;
                     shd[wv][3] = C;  shd[wv][4] = dot; shd[wv][5] = vA; }
    __syncthreads();
    if (tid == 0) {
        double a0 = 0, a1 = 0, a2 = 0, a3 = 0, a5 = 0, a6 = 0;
        #pragma unroll
        for (int i = 0; i < 4; ++i) {
            a0 += shd[i][0]; a1 += shd[i][1]; a2 += shd[i][2];
            a3 += shd[i][3]; a5 += shd[i][4]; a6 += shd[i][5];
        }
        double wsum = a6 - a5 + 0.001 * a3;   // v·A - rows·Scol + eps·C
        out[0] = (float)(0.6 * (wsum / (double)NPIX));
        out[1] = (float)(1.0 - (2.0 * a0 + 1e-6) / (a1 + a2 + 1e-6));
    }
}

extern "C" void kernel_launch(void* const* d_in, const int* in_sizes, int n_in,
                              void* d_out, int out_size, void* d_ws, size_t ws_size,
                              hipStream_t stream) {
    const float* inp = (const float*)d_in[0];
    const float* tgt = (const float*)d_in[1];
    float* out = (float*)d_out;
    WS* ws = (WS*)d_ws;

    hipMemsetAsync(&ws->done, 0, sizeof(unsigned int), stream);
    fused_kernel<<<NTOT, BLOCK, 0, stream>>>(inp, tgt, ws, out);
}